// Round 2
// baseline (86.636 us; speedup 1.0000x reference)
//
#include <hip/hip_runtime.h>

// Problem constants (from reference setup_inputs / OUTPUT_LENGTH)
#define B_SZ 16
#define N_SZ 512
#define C_SZ 512
#define L_SZ 2048
#define ROW4 (C_SZ / 4)                     // 128 float4 per row
#define THREADS 256
#define ROWS_PER_BLK 16                     // output rows per block (32 KB contiguous)
#define BLKS_PER_BATCH (L_SZ / ROWS_PER_BLK) // 128
#define NBLOCKS (B_SZ * BLKS_PER_BATCH)     // 2048
#define NWAVES (THREADS / 64)               // 4

// Native clang vector type: __builtin_nontemporal_* requires a real vector,
// not HIP's float4 struct.
typedef float f32x4 __attribute__((ext_vector_type(4)));

// ---------------------------------------------------------------------------
// Single fused kernel. Each block:
//   1. recomputes the batch's duration cumsum (512 elems, shfl-scan, ~2 KB read
//      that is L2-broadcast across the 128 blocks sharing the batch),
//   2. binary-searches phoneme index for its 16 contiguous output rows,
//   3. streams 16 rows x 512 floats: out[b,l,:] = enc[b,p,:] or 0.
// XCD swizzle: bid%8 -> XCD owns a contiguous 256-block chunk = 2 whole
// batches, so each XCD's enc working set is 2 MB (fits 4 MiB L2).
// Nontemporal stores keep the 64 MiB write stream from evicting enc.
// ---------------------------------------------------------------------------
__global__ __launch_bounds__(THREADS) void lenreg_fused_kernel(
    const float* __restrict__ enc,   // (B, N, C) fp32
    const float* __restrict__ ldur,  // (B, N, 1) fp32
    float* __restrict__ out)         // (B, L, C) fp32
{
    __shared__ int ends_s[N_SZ];        // inclusive cumsum of durations
    __shared__ int wtot[NWAVES];
    __shared__ int pl[ROWS_PER_BLK];    // phoneme index per row, -1 = zero

    const int tid  = threadIdx.x;
    const int lane = tid & 63;
    const int w    = tid >> 6;

    // XCD-contiguous swizzle (2048 % 8 == 0 -> bijective).
    const int bid = blockIdx.x;
    const int swz = (bid & 7) * (NBLOCKS / 8) + (bid >> 3);
    const int b   = swz >> 7;                               // / BLKS_PER_BATCH
    const int l0  = (swz & (BLKS_PER_BATCH - 1)) * ROWS_PER_BLK;

    // ---- durations (reference math) + inclusive scan, 2 elems/thread ----
    const float2 ld2 = ((const float2*)(ldur + b * N_SZ))[tid];
    const int d0 = (ld2.x > 0.0f) ? (int)floorf(exp2f(ld2.x) + 1e-4f) : 0;
    const int d1 = (ld2.y > 0.0f) ? (int)floorf(exp2f(ld2.y) + 1e-4f) : 0;

    int scan = d0 + d1;                  // pair sum
    #pragma unroll
    for (int o = 1; o < 64; o <<= 1) {
        const int v = __shfl_up(scan, o, 64);
        if (lane >= o) scan += v;
    }
    if (lane == 63) wtot[w] = scan;
    __syncthreads();

    int base = 0;
    #pragma unroll
    for (int i = 0; i < NWAVES; ++i)
        if (i < w) base += wtot[i];

    const int e1 = base + scan;          // ends[2*tid+1]
    ends_s[2 * tid + 1] = e1;            // stride-2 int: 2-way LDS alias (free)
    ends_s[2 * tid]     = e1 - d1;
    __syncthreads();

    // ---- per-row lower_bound: smallest i with ends[i] > l ----
    // (then ends[i-1] <= l  =>  starts[i] <= l < ends[i], and dur[i] > 0)
    if (tid < ROWS_PER_BLK) {
        const int l = l0 + tid;
        int lo = 0, hi = N_SZ;
        #pragma unroll 1
        while (lo < hi) {                // exactly 9 uniform iterations
            const int mid = (lo + hi) >> 1;
            if (ends_s[mid] > l) hi = mid; else lo = mid + 1;
        }
        pl[tid] = (lo < N_SZ) ? lo : -1;
    }
    __syncthreads();

    // ---- copy 16 rows x 512 floats; 8 float4 per thread ----
    const f32x4* enc4 = (const f32x4*)enc + (size_t)b * N_SZ * ROW4;
    f32x4*       out4 = (f32x4*)out + ((size_t)b * L_SZ + l0) * ROW4;
    const int c4 = tid & (ROW4 - 1);
    const int rh = tid >> 7;             // 0/1: two rows per iteration
    #pragma unroll
    for (int rr = 0; rr < 8; ++rr) {
        const int r = rr * 2 + rh;
        const int p = pl[r];             // LDS broadcast, wave-uniform
        f32x4 v = (f32x4)(0.0f);
        if (p >= 0) v = enc4[p * ROW4 + c4];
        __builtin_nontemporal_store(v, out4 + r * ROW4 + c4);
    }
}

extern "C" void kernel_launch(void* const* d_in, const int* in_sizes, int n_in,
                              void* d_out, int out_size, void* d_ws, size_t ws_size,
                              hipStream_t stream) {
    const float* enc = (const float*)d_in[0];   // (16, 512, 512) fp32
    const float* ld  = (const float*)d_in[1];   // (16, 512, 1)  fp32
    float* out       = (float*)d_out;           // (16, 2048, 512) fp32

    lenreg_fused_kernel<<<NBLOCKS, THREADS, 0, stream>>>(enc, ld, out);
}